// Round 5
// baseline (282.555 us; speedup 1.0000x reference)
//
#include <hip/hip_runtime.h>

// SSIM (win=7, valid) fused single-pass kernel for (32,3,512,512) fp32 inputs.
// 96 planes of 512x512 -> mean over 96x506x506 S map.
//
// R7: register row-ring — every input row loaded exactly ONCE per wave.
// R3-R6 counters: VALU<=26%, LDS 0, HBM<=32%, LLC-fed dispatch same speed as
// HBM-fed; per-wave row-step ~2600 cyc vs ~800 cyc VALU -> bound by the shared
// vmem request path, i.e. requests-per-output. So: kill the top-row re-read.
//   - Ring of 8 row-pairs (x,y) in registers, statically indexed (period-8
//     full unroll; runtime-indexed arrays would go to scratch). Body j:
//     vadd(slot (j+6)%8) -> hssim -> vsub(slot j%8) -> prefetch row j+8 into
//     the freed slot (issue->use = one full body, no sched pins; R6 showed
//     sched_barrier(0) pinning regresses).
//   - Per output row: 4 vmem wave-instrs (was 8). Total request traffic
//     ~290 MB (was ~530) for a 201 MB problem.
//   - RSTRIP=22 (23 strips, 506=22*23 exact): halo amplification 1.27 (was
//     1.55). 2208 single-wave blocks; VGPR ~230 -> 2 waves/SIMD = 8 waves/CU,
//     which matches the effective occupancy ever achieved. No barriers/LDS.
//   - Kept: XCD-chunked swizzle (2208=8*276, bijective), raw-49 SSIM algebra,
//     rcp+Newton division, 8 cols/lane with shfl_down halo prefix.

namespace {
constexpr int W       = 512;
constexpr int HH      = 512;
constexpr int NIMG    = 96;
constexpr int OW      = 506;
constexpr int RSTRIP  = 22;               // 23 strips * 22 rows = 506 output rows
constexpr int NSTRIP  = 23;
constexpr int WAVES   = NIMG * NSTRIP;    // 2208 (one wave per block)
constexpr int NXCD    = 8;
constexpr int CPX     = WAVES / NXCD;     // 276 (2208 % 8 == 0 -> bijective)
constexpr float C1s   = 0.2401f;          // C1 * 49^2
constexpr float C2s   = 2.1609f;          // C2 * 49^2
constexpr float COVN  = 49.0f / 48.0f;    // NP/(NP-1)
constexpr double NPIX = 96.0 * 506.0 * 506.0;   // 24,579,456
}

__device__ __forceinline__ void load8(const float* __restrict__ p, float (&v)[8])
{
    float4 a = *(const float4*)(p);
    float4 b = *(const float4*)(p + 4);
    v[0] = a.x; v[1] = a.y; v[2] = a.z; v[3] = a.w;
    v[4] = b.x; v[5] = b.y; v[6] = b.z; v[7] = b.w;
}

__device__ __forceinline__ void vadd(float (&V)[5][8], const float (&x)[8], const float (&y)[8])
{
#pragma unroll
    for (int k = 0; k < 8; k++) {
        V[0][k] += x[k];
        V[1][k] += y[k];
        V[2][k] = fmaf(x[k], x[k], V[2][k]);
        V[3][k] = fmaf(y[k], y[k], V[3][k]);
        V[4][k] = fmaf(x[k], y[k], V[4][k]);
    }
}

__device__ __forceinline__ void vsub(float (&V)[5][8], const float (&x)[8], const float (&y)[8])
{
#pragma unroll
    for (int k = 0; k < 8; k++) {
        V[0][k] -= x[k];
        V[1][k] -= y[k];
        V[2][k] = fmaf(-x[k], x[k], V[2][k]);
        V[3][k] = fmaf(-y[k], y[k], V[3][k]);
        V[4][k] = fmaf(-x[k], y[k], V[4][k]);
    }
}

// horizontal 7-sums (in-lane prefix + 6 halo values from lane+1) and the
// SSIM evaluation on raw 49-sums. Output col c0+k covers cols c0+k..c0+k+6.
__device__ __forceinline__ void hssim(const float (&V)[5][8], float& sacc, int c0)
{
    float Hh[5][8];
#pragma unroll
    for (int q = 0; q < 5; q++) {
        float P[8];
        P[0] = V[q][0];
#pragma unroll
        for (int k = 1; k < 8; k++) P[k] = P[k - 1] + V[q][k];
        const float Pn0 = __shfl_down(P[0], 1);
        const float Pn1 = __shfl_down(P[1], 1);
        const float Pn2 = __shfl_down(P[2], 1);
        const float Pn3 = __shfl_down(P[3], 1);
        const float Pn4 = __shfl_down(P[4], 1);
        const float Pn5 = __shfl_down(P[5], 1);
        const float T = P[7];
        Hh[q][0] = P[6];
        Hh[q][1] = T - P[0];
        Hh[q][2] = (T - P[1]) + Pn0;
        Hh[q][3] = (T - P[2]) + Pn1;
        Hh[q][4] = (T - P[3]) + Pn2;
        Hh[q][5] = (T - P[4]) + Pn3;
        Hh[q][6] = (T - P[5]) + Pn4;
        Hh[q][7] = (T - P[6]) + Pn5;
    }

    //   A=49ux B=49uy P=49uxx Q=49uyy R=49uxy
    //   num = (2AB + C1*49^2) * (2*COVN*(49R - AB) + C2*49^2)
    //   den = (A^2+B^2 + C1*49^2) * (COVN*(49(P+Q) - A^2-B^2) + C2*49^2)
#pragma unroll
    for (int k = 0; k < 8; k++) {
        float A = Hh[0][k], B = Hh[1][k];
        float Pq = Hh[2][k], Qq = Hh[3][k], R = Hh[4][k];
        float AB  = A * B;
        float a1  = fmaf(2.0f, AB, C1s);
        float ab2 = fmaf(A, A, B * B);
        float b1  = ab2 + C1s;
        float tt  = fmaf(49.0f, R, -AB);
        float a2  = fmaf(2.0f * COVN, tt, C2s);
        float pq  = Pq + Qq;
        float t2  = fmaf(49.0f, pq, -ab2);
        float b2  = fmaf(COVN, t2, C2s);
        float num = a1 * a2;
        float den = b1 * b2;
        float r   = __builtin_amdgcn_rcpf(den);
        r = r * fmaf(-den, r, 2.0f);        // 1 Newton step -> ~0.5 ulp
        float S = num * r;
        if (c0 + k < OW) sacc += S;
    }
}

// One output row j (r0-relative). Ring slot SADD=(j+6)%8 holds row j+6,
// slot SSUB=j%8 holds row j. After vsub frees SSUB, prefetch row j+8 into it
// (consumed at body j+2 -> one full body of cover).
template<int SADD, int SSUB, bool PRE>
__device__ __forceinline__ void body(int j, int r0,
        const float* __restrict__ xb, const float* __restrict__ yb,
        float (&rx)[8][8], float (&ry)[8][8],
        float (&V)[5][8], float& sacc, int c0)
{
    vadd(V, rx[SADD], ry[SADD]);             // window complete: rows j..j+6
    hssim(V, sacc, c0);
    vsub(V, rx[SSUB], ry[SSUB]);             // drop row j (register-held)
    if (PRE) {
        load8(xb + (size_t)(r0 + j + 8) * W, rx[SSUB]);
        load8(yb + (size_t)(r0 + j + 8) * W, ry[SSUB]);
    }
}

__global__ __launch_bounds__(64, 2) void ssim_main(const float* __restrict__ X,
                                                   const float* __restrict__ Y,
                                                   double* __restrict__ partial)
{
    const int lane = threadIdx.x & 63;

    // XCD-chunked swizzle: consecutive logical blocks land on one XCD.
    const int bid = blockIdx.x;
    const int gw  = (bid % NXCD) * CPX + bid / NXCD;   // 0..2207

    const int img   = gw / NSTRIP;
    const int strip = gw - img * NSTRIP;
    const int r0    = strip * RSTRIP;             // first output row of strip
    const int c0    = lane * 8;                   // this lane's 8 columns

    const float* xb = X + (size_t)img * (W * HH) + c0;
    const float* yb = Y + (size_t)img * (W * HH) + c0;

    // register ring: slot s holds row (r0-relative) with rho % 8 == s
    float rx[8][8], ry[8][8];

    // warm-up: load rows 0..7 (slots 0..7) — 32 dwordx4 in flight at start
#pragma unroll
    for (int r = 0; r < 8; r++) {
        load8(xb + (size_t)(r0 + r) * W, rx[r]);
        load8(yb + (size_t)(r0 + r) * W, ry[r]);
    }

    // vertical running sums V[0]=x V[1]=y V[2]=x^2 V[3]=y^2 V[4]=xy
    float V[5][8];
#pragma unroll
    for (int q = 0; q < 5; q++)
#pragma unroll
        for (int k = 0; k < 8; k++) V[q][k] = 0.0f;

    // rows 0..5 into V (row 6 consumed by body 0, row 7 by body 1)
#pragma unroll
    for (int r = 0; r < 6; r++) vadd(V, rx[r], ry[r]);

    float sacc = 0.0f;

    // bodies j=0..15: two turns of the period-8 ring (static slot indices)
#pragma unroll 1
    for (int jb = 0; jb < 16; jb += 8) {
        body<6, 0, true>(jb + 0, r0, xb, yb, rx, ry, V, sacc, c0);
        body<7, 1, true>(jb + 1, r0, xb, yb, rx, ry, V, sacc, c0);
        body<0, 2, true>(jb + 2, r0, xb, yb, rx, ry, V, sacc, c0);
        body<1, 3, true>(jb + 3, r0, xb, yb, rx, ry, V, sacc, c0);
        body<2, 4, true>(jb + 4, r0, xb, yb, rx, ry, V, sacc, c0);
        body<3, 5, true>(jb + 5, r0, xb, yb, rx, ry, V, sacc, c0);
        body<4, 6, true>(jb + 6, r0, xb, yb, rx, ry, V, sacc, c0);
        body<5, 7, true>(jb + 7, r0, xb, yb, rx, ry, V, sacc, c0);
    }
    // tail j=16..21; last prefetch at j=19 loads row 27 = last needed row
    body<6, 0, true >(16, r0, xb, yb, rx, ry, V, sacc, c0);
    body<7, 1, true >(17, r0, xb, yb, rx, ry, V, sacc, c0);
    body<0, 2, true >(18, r0, xb, yb, rx, ry, V, sacc, c0);
    body<1, 3, true >(19, r0, xb, yb, rx, ry, V, sacc, c0);
    body<2, 4, false>(20, r0, xb, yb, rx, ry, V, sacc, c0);
    body<3, 5, false>(21, r0, xb, yb, rx, ry, V, sacc, c0);

    // wave reduction -> one partial per block (single wave, no LDS/barrier)
#pragma unroll
    for (int off = 32; off > 0; off >>= 1)
        sacc += __shfl_down(sacc, off);
    if (lane == 0) partial[bid] = (double)sacc;
}

__global__ void ssim_finalize(const double* __restrict__ partial, float* __restrict__ out)
{
    __shared__ double ws[4];
    const int t = threadIdx.x;               // 256 threads
    double s = 0.0;
    for (int i = t; i < WAVES; i += 256) s += partial[i];
#pragma unroll
    for (int off = 32; off > 0; off >>= 1)
        s += __shfl_down(s, off);
    if ((t & 63) == 0) ws[t >> 6] = s;
    __syncthreads();
    if (t == 0) out[0] = (float)(((ws[0] + ws[1]) + (ws[2] + ws[3])) / NPIX);
}

extern "C" void kernel_launch(void* const* d_in, const int* in_sizes, int n_in,
                              void* d_out, int out_size, void* d_ws, size_t ws_size,
                              hipStream_t stream)
{
    const float* X = (const float*)d_in[0];   // input_tensor (32,3,512,512) fp32
    const float* Y = (const float*)d_in[1];   // target       (32,3,512,512) fp32
    float* out = (float*)d_out;               // scalar fp32
    double* partial = (double*)d_ws;          // 2208 doubles

    ssim_main<<<dim3(WAVES), 64, 0, stream>>>(X, Y, partial);
    ssim_finalize<<<1, 256, 0, stream>>>(partial, out);
}

// Round 7
// 252.752 us; speedup vs baseline: 1.1179x; 1.1179x over previous
//
#include <hip/hip_runtime.h>

// SSIM (win=7, valid) fused single-pass kernel for (32,3,512,512) fp32 inputs.
// 96 planes of 512x512 -> mean over 96x506x506 S map.
//
// R8 (resubmit — previous round was an infra failure, kernel never ran):
// full 16B/lane coalescing. R1-R7 model closure: dur == traffic / ~2.5TB/s
// in every round (latency-, occupancy-, MLP-insensitive) -> bound by the
// request path's service rate FOR THIS PATTERN. Old load8 = 2x dwordx4 at
// 32B lane stride: touches 16 lines/instr, half-consumed, re-touched by the
// pair instr -> 2x line-transactions/byte. 6.3 (copy ceiling) / 2 / 1.27
// (strip halo) = 2.48 TB/s = measured wall. Fix: lane-contiguous panels.
//   - Lane l owns cols {4l..4l+3} (panel A) and {256+4l..+3} (panel B); each
//     row-array load = 2 dwordx4, each 1KB contiguous, 8 lines, single-touch.
//   - Horizontal 7-sum per panel: 4-wide in-lane prefix + shfl_down(1)/(2)
//     halo. Seam outputs (cols 250..255, panel-A lanes 62/63) corrected with
//     broadcasts of panel-B lane 0/1 prefixes. Panel B lanes 62(k>=2)/63
//     masked (cols > 505).
//   - Everything else = R5 (best, 104us): RSTRIP=11/46 strips, 4416 waves in
//     1104 4-wave blocks, XCD-chunked swizzle, top-row reread (on-die per
//     FETCH evidence), raw-49 SSIM algebra, rcp+Newton. No barriers/LDS in
//     the hot loop. No sched pins (R6 lesson), no register ring (R7 spills).

namespace {
constexpr int W       = 512;
constexpr int HH      = 512;
constexpr int NIMG    = 96;
constexpr int OW      = 506;
constexpr int RSTRIP  = 11;               // 46 strips * 11 rows = 506 output rows
constexpr int NSTRIP  = 46;
constexpr int WAVES   = NIMG * NSTRIP;    // 4416
constexpr int BLOCKS  = WAVES / 4;        // 1104 blocks x 4 waves
constexpr int NXCD    = 8;
constexpr int CPX     = BLOCKS / NXCD;    // 138 (1104 % 8 == 0 -> bijective)
constexpr float C1s   = 0.2401f;          // C1 * 49^2
constexpr float C2s   = 2.1609f;          // C2 * 49^2
constexpr float COVN  = 49.0f / 48.0f;    // NP/(NP-1)
constexpr double NPIX = 96.0 * 506.0 * 506.0;   // 24,579,456
}

// p points at this lane's panel-A float4 within the row (base + row*512 + 4*lane)
__device__ __forceinline__ void loadrow(const float* __restrict__ p, float (&v)[2][4])
{
    float4 a = *(const float4*)(p);
    float4 b = *(const float4*)(p + 256);   // panel B: +1024 bytes
    v[0][0] = a.x; v[0][1] = a.y; v[0][2] = a.z; v[0][3] = a.w;
    v[1][0] = b.x; v[1][1] = b.y; v[1][2] = b.z; v[1][3] = b.w;
}

__device__ __forceinline__ void vadd(float (&V)[5][2][4], const float (&x)[2][4], const float (&y)[2][4])
{
#pragma unroll
    for (int p = 0; p < 2; p++)
#pragma unroll
        for (int k = 0; k < 4; k++) {
            V[0][p][k] += x[p][k];
            V[1][p][k] += y[p][k];
            V[2][p][k] = fmaf(x[p][k], x[p][k], V[2][p][k]);
            V[3][p][k] = fmaf(y[p][k], y[p][k], V[3][p][k]);
            V[4][p][k] = fmaf(x[p][k], y[p][k], V[4][p][k]);
        }
}

__device__ __forceinline__ void vsub(float (&V)[5][2][4], const float (&x)[2][4], const float (&y)[2][4])
{
#pragma unroll
    for (int p = 0; p < 2; p++)
#pragma unroll
        for (int k = 0; k < 4; k++) {
            V[0][p][k] -= x[p][k];
            V[1][p][k] -= y[p][k];
            V[2][p][k] = fmaf(-x[p][k], x[p][k], V[2][p][k]);
            V[3][p][k] = fmaf(-y[p][k], y[p][k], V[3][p][k]);
            V[4][p][k] = fmaf(-x[p][k], y[p][k], V[4][p][k]);
        }
}

// horizontal 7-sums + SSIM on raw 49-sums for both panels.
// Panel A covers output cols 4l+k (all valid); panel B covers 256+4l+k
// (valid iff 4l+k <= 249). Seam (A lanes 62/63) uses panel-B lane 0/1 data.
__device__ __forceinline__ void hssim(const float (&V)[5][2][4], float& sacc, int lane)
{
    float HA[5][4], HB[5][4];
#pragma unroll
    for (int q = 0; q < 5; q++) {
        const float a0 = V[q][0][0];
        const float a1 = a0 + V[q][0][1];
        const float a2 = a1 + V[q][0][2];
        const float a3 = a2 + V[q][0][3];
        const float b0 = V[q][1][0];
        const float b1 = b0 + V[q][1][1];
        const float b2 = b1 + V[q][1][2];
        const float b3 = b2 + V[q][1][3];

        float n1P2 = __shfl_down(a2, 1);    // lane+1 prefix(0..2)
        float n1P3 = __shfl_down(a3, 1);    // lane+1 prefix(0..3)
        float n2P0 = __shfl_down(a0, 2);    // lane+2 prefix(0)
        float n2P1 = __shfl_down(a1, 2);    // lane+2 prefix(0..1)
        float m1P2 = __shfl_down(b2, 1);
        float m1P3 = __shfl_down(b3, 1);
        float m2P0 = __shfl_down(b0, 2);
        float m2P1 = __shfl_down(b1, 2);

        // seam sources: panel-B prefixes of lanes 0 and 1 (cols 256.. / 260..)
        const float sb00 = __shfl(b0, 0), sb10 = __shfl(b1, 0);
        const float sb20 = __shfl(b2, 0), sb30 = __shfl(b3, 0);
        const float sb01 = __shfl(b0, 1), sb11 = __shfl(b1, 1);
        if (lane == 62) { n2P0 = sb00; n2P1 = sb10; }
        if (lane == 63) { n1P2 = sb20; n1P3 = sb30; n2P0 = sb01; n2P1 = sb11; }

        HA[q][0] = a3 + n1P2;                    // cols c..c+6
        HA[q][1] = (a3 - a0) + n1P3;
        HA[q][2] = (a3 - a1) + (n1P3 + n2P0);
        HA[q][3] = (a3 - a2) + (n1P3 + n2P1);
        HB[q][0] = b3 + m1P2;
        HB[q][1] = (b3 - b0) + m1P3;
        HB[q][2] = (b3 - b1) + (m1P3 + m2P0);
        HB[q][3] = (b3 - b2) + (m1P3 + m2P1);
    }

    //   A=49ux B=49uy P=49uxx Q=49uyy R=49uxy
    //   num = (2AB + C1*49^2) * (2*COVN*(49R - AB) + C2*49^2)
    //   den = (A^2+B^2 + C1*49^2) * (COVN*(49(P+Q) - A^2-B^2) + C2*49^2)
    const int lk = lane * 4;
#pragma unroll
    for (int k = 0; k < 4; k++) {
        // panel A: always a valid output column
        {
            float A = HA[0][k], B = HA[1][k];
            float Pq = HA[2][k], Qq = HA[3][k], R = HA[4][k];
            float AB  = A * B;
            float a1  = fmaf(2.0f, AB, C1s);
            float ab2 = fmaf(A, A, B * B);
            float b1  = ab2 + C1s;
            float tt  = fmaf(49.0f, R, -AB);
            float a2  = fmaf(2.0f * COVN, tt, C2s);
            float pq  = Pq + Qq;
            float t2  = fmaf(49.0f, pq, -ab2);
            float b2  = fmaf(COVN, t2, C2s);
            float num = a1 * a2;
            float den = b1 * b2;
            float r   = __builtin_amdgcn_rcpf(den);
            r = r * fmaf(-den, r, 2.0f);
            sacc += num * r;
        }
        // panel B: valid iff col 256+4l+k <= 505
        {
            float A = HB[0][k], B = HB[1][k];
            float Pq = HB[2][k], Qq = HB[3][k], R = HB[4][k];
            float AB  = A * B;
            float a1  = fmaf(2.0f, AB, C1s);
            float ab2 = fmaf(A, A, B * B);
            float b1  = ab2 + C1s;
            float tt  = fmaf(49.0f, R, -AB);
            float a2  = fmaf(2.0f * COVN, tt, C2s);
            float pq  = Pq + Qq;
            float t2  = fmaf(49.0f, pq, -ab2);
            float b2  = fmaf(COVN, t2, C2s);
            float num = a1 * a2;
            float den = b1 * b2;
            float r   = __builtin_amdgcn_rcpf(den);
            r = r * fmaf(-den, r, 2.0f);
            float S = num * r;
            if (lk + k <= 249) sacc += S;
        }
    }
}

__global__ __launch_bounds__(256, 2) void ssim_main(const float* __restrict__ X,
                                                    const float* __restrict__ Y,
                                                    double* __restrict__ partial)
{
    __shared__ float wsum[4];

    const int t    = threadIdx.x;
    const int lane = t & 63;
    const int wid  = t >> 6;                      // wave in block: 0..3

    // XCD-chunked swizzle: consecutive logical blocks land on one XCD.
    const int bid  = blockIdx.x;
    const int swz  = (bid % NXCD) * CPX + bid / NXCD;

    const int gw    = swz * 4 + wid;              // global wave id: 0..4415
    const int img   = gw / NSTRIP;
    const int strip = gw - img * NSTRIP;
    const int r0    = strip * RSTRIP;             // first output row of strip

    // base pointers at this lane's panel-A float4
    const float* xb = X + (size_t)img * (W * HH) + lane * 4;
    const float* yb = Y + (size_t)img * (W * HH) + lane * 4;

    // vertical running sums V[q][panel][k]:
    // q: 0=x 1=y 2=x^2 3=y^2 4=xy
    float V[5][2][4];
#pragma unroll
    for (int q = 0; q < 5; q++)
#pragma unroll
        for (int p = 0; p < 2; p++)
#pragma unroll
            for (int k = 0; k < 4; k++) V[q][p][k] = 0.0f;

    // top row of the first window (kept for the j=0 subtract)
    float xo[2][4], yo[2][4];

    // warm-up: rows r0 .. r0+5
#pragma unroll
    for (int r = 0; r < 6; r++) {
        float xs[2][4], ys[2][4];
        loadrow(xb + (size_t)(r0 + r) * W, xs);
        loadrow(yb + (size_t)(r0 + r) * W, ys);
        vadd(V, xs, ys);
        if (r == 0) {
#pragma unroll
            for (int p = 0; p < 2; p++)
#pragma unroll
                for (int k = 0; k < 4; k++) { xo[p][k] = xs[p][k]; yo[p][k] = ys[p][k]; }
        }
    }

    // bottom row of the first window
    float xn[2][4], yn[2][4];
    loadrow(xb + (size_t)(r0 + 6) * W, xn);
    loadrow(yb + (size_t)(r0 + 6) * W, yn);

    float sacc = 0.0f;

#pragma unroll 1
    for (int j = 0; j < RSTRIP; j++) {
        // add bottom row (r0 + j + 6), already in registers
        vadd(V, xn, yn);

        // prefetch rows for iteration j+1: bottom r0+j+7, top r0+j+1
        float xnp[2][4], ynp[2][4], xop[2][4], yop[2][4];
        int rb = r0 + j + 7; if (rb > HH - 1) rb = HH - 1;   // clamped; unused on last iter
        loadrow(xb + (size_t)rb * W, xnp);
        loadrow(yb + (size_t)rb * W, ynp);
        loadrow(xb + (size_t)(r0 + j + 1) * W, xop);
        loadrow(yb + (size_t)(r0 + j + 1) * W, yop);

        // horizontal 7-sums + SSIM for this row
        hssim(V, sacc, lane);

        // subtract top row (r0 + j), already in registers
        vsub(V, xo, yo);

        // rotate prefetched rows into place
#pragma unroll
        for (int p = 0; p < 2; p++)
#pragma unroll
            for (int k = 0; k < 4; k++) {
                xn[p][k] = xnp[p][k]; yn[p][k] = ynp[p][k];
                xo[p][k] = xop[p][k]; yo[p][k] = yop[p][k];
            }
    }

    // reduction: wave shuffle -> LDS -> one partial per block (no atomics)
#pragma unroll
    for (int off = 32; off > 0; off >>= 1)
        sacc += __shfl_down(sacc, off);
    if (lane == 0) wsum[wid] = sacc;
    __syncthreads();
    if (t == 0)
        partial[blockIdx.x] = (double)((wsum[0] + wsum[1]) + (wsum[2] + wsum[3]));
}

__global__ void ssim_finalize(const double* __restrict__ partial, float* __restrict__ out)
{
    __shared__ double ws[4];
    const int t = threadIdx.x;               // 256 threads
    double s = 0.0;
    for (int i = t; i < BLOCKS; i += 256) s += partial[i];
#pragma unroll
    for (int off = 32; off > 0; off >>= 1)
        s += __shfl_down(s, off);
    if ((t & 63) == 0) ws[t >> 6] = s;
    __syncthreads();
    if (t == 0) out[0] = (float)(((ws[0] + ws[1]) + (ws[2] + ws[3])) / NPIX);
}

extern "C" void kernel_launch(void* const* d_in, const int* in_sizes, int n_in,
                              void* d_out, int out_size, void* d_ws, size_t ws_size,
                              hipStream_t stream)
{
    const float* X = (const float*)d_in[0];   // input_tensor (32,3,512,512) fp32
    const float* Y = (const float*)d_in[1];   // target       (32,3,512,512) fp32
    float* out = (float*)d_out;               // scalar fp32
    double* partial = (double*)d_ws;          // 1104 doubles

    ssim_main<<<dim3(BLOCKS), 256, 0, stream>>>(X, Y, partial);
    ssim_finalize<<<1, 256, 0, stream>>>(partial, out);
}